// Round 15
// baseline (8416.006 us; speedup 1.0000x reference)
//
#include <hip/hip_runtime.h>
#include <math.h>

#define BB 64
#define TT 512
#define DD 128
#define HH 512
#define NROW 16
#define NCG 16
#define NWG 256
#define TAGM 511u

typedef unsigned uint4v __attribute__((ext_vector_type(4)));

// One agent-coherent 16B load: all 4 batches of one column. THE detect op.
#define LOADX4(d, ptr)                                                        \
  asm volatile("global_load_dwordx4 %0, %1, off sc0 sc1"                      \
               : "=v"(d) : "v"(ptr) : "memory")

// WG barrier ordering LDS only — global stores stay in flight across steps.
#define BARRIER_LGKM() asm volatile("s_waitcnt lgkmcnt(0)\n\ts_barrier" ::: "memory")

// ---------------------------------------------------------------------------
// Pre-kernel: utT2[cg][k][128], inner ii = 2*lane + d -> U_g[cg*32+(lane&31)][k],
// g = (lane>>5)*2 + d. Feeds register-resident per-lane U (float2 per k).
// ---------------------------------------------------------------------------
__global__ __launch_bounds__(256) void uT2_kernel(
    const float* __restrict__ Ui_w, const float* __restrict__ Uf_w,
    const float* __restrict__ Uo_w, const float* __restrict__ Ug_w,
    float* __restrict__ utT2)
{
    const int cg = blockIdx.x;
    for (int idx = threadIdx.x; idx < HH * 128; idx += 256) {
        const int k = idx >> 7, ii = idx & 127;
        const int l = ii >> 1, d = ii & 1;
        const int j = cg * 32 + (l & 31);
        const int g = ((l >> 5) << 1) + d;
        const float* U = (g == 0) ? Ui_w : (g == 1) ? Uf_w : (g == 2) ? Uo_w : Ug_w;
        utT2[((size_t)cg * HH + k) * 128 + ii] = U[(size_t)j * HH + k];
    }
}

// ---------------------------------------------------------------------------
// Persistent kernel. 256 WGs: row r = wg&15 (4 batches), cg = wg>>4 (32 cols).
// 8 waves, k-slice 64/wave, U register-resident. One lgkm barrier per step.
// h exchange: hpub[2][row][512col][4b], mantissa-tagged (9 LSB = gen mod 512).
// Detect: ONE dwordx4/lane; HALF-SPLIT — run k4 0-7 as soon as producer A's
// 32 cols land, overlap producer B's skew/latency; s_sleep(1) retry backoff.
// ---------------------------------------------------------------------------
__global__ __launch_bounds__(512, 2) void lstm_persist(
    const float* __restrict__ utT2,
    const float* __restrict__ Ui_w, const float* __restrict__ Uf_w,
    const float* __restrict__ Ug_w,
    const float* __restrict__ x,
    const float* __restrict__ Wi_w, const float* __restrict__ Wi_b,
    const float* __restrict__ Wf_w, const float* __restrict__ Wf_b,
    const float* __restrict__ Wo_w, const float* __restrict__ Wo_b,
    const float* __restrict__ Wg_w, const float* __restrict__ Wg_b,
    float* __restrict__ b_i, float* __restrict__ b_f,
    float* __restrict__ b_o, float* __restrict__ b_g,
    unsigned* __restrict__ hpub)   // [2][NROW][512][4] tagged f32
{
    __shared__ float  hlds[8][4][64];         //  8 KB own-wave h slice
    __shared__ float2 red2[2][8][2][128];     // 32 KB partials (parity dbuf)
    __shared__ float  xps[2][4][128];         //  4 KB xp (parity dbuf)
    __shared__ float  shout[2][4][128];       //  4 KB outputs (parity dbuf)
    __shared__ float  xlds[2][4][128];        //  4 KB x rows (parity dbuf)

    const int tid  = threadIdx.x;
    const int w    = tid >> 6;
    const int lane = tid & 63;
    const int wg   = blockIdx.x;
    const int r    = wg & 15;
    const int cg   = wg >> 4;
    const int k0   = w << 6;

    // register-resident U slice: lane owns (col=lane&31, gates gp*2, gp*2+1)
    float2 u2[64];
    {
        const float* ub = utT2 + ((size_t)cg * HH + k0) * 128 + 2 * lane;
        #pragma unroll
        for (int k = 0; k < 64; ++k) u2[k] = *(const float2*)(ub + (size_t)k * 128);
    }

    // pointwise state (threads 0..127): b4 = tid>>5, col = tid&31
    float creg = 0.f, uid = 0.f, ufd = 0.f, ugd = 0.f;
    int jjg = 0, b4 = 0;
    if (tid < 128) {
        jjg = cg * 32 + (tid & 31);
        b4  = tid >> 5;
        uid = Ui_w[(size_t)jjg * HH + jjg];
        ufd = Uf_w[(size_t)jjg * HH + jjg];
        ugd = Ug_w[(size_t)jjg * HH + jjg];
    }

    // xproj registers (waves 4-7): gate ga = w-4, col = lane&31, dh = lane>>5
    float4 wreg[16];
    float  wbias = 0.f;
    const int ga = (w >= 4) ? (w - 4) : 0;
    if (w >= 4) {
        const int col = lane & 31, dh = lane >> 5;
        const float* Ws = (ga == 0) ? Wi_w : (ga == 1) ? Wf_w : (ga == 2) ? Wo_w : Wg_w;
        const float* Bs = (ga == 0) ? Wi_b : (ga == 1) ? Wf_b : (ga == 2) ? Wo_b : Wg_b;
        const float* base = Ws + (size_t)(cg * 32 + col) * DD + dh * 64;
        #pragma unroll
        for (int k4 = 0; k4 < 16; ++k4) wreg[k4] = *(const float4*)(base + k4 * 4);
        wbias = Bs[cg * 32 + col];
    }

    // ---- prime: stage x(0),x(1); compute xp(0) -> xps[0] ----
    if (w == 4) {
        const int bx = lane >> 4, c8 = lane & 15;
        #pragma unroll
        for (int u = 0; u < 2; ++u) {
            const float* xs = x + ((size_t)(r * 4 + bx) * TT + u) * DD + c8 * 8;
            *(float4*)&xlds[u][bx][c8 * 8]     = *(const float4*)(xs);
            *(float4*)&xlds[u][bx][c8 * 8 + 4] = *(const float4*)(xs + 4);
        }
    }
    __syncthreads();
    if (w >= 4) {
        const int col = lane & 31, dh = lane >> 5;
        #pragma unroll
        for (int b = 0; b < 4; ++b) {
            float a = 0.f;
            #pragma unroll
            for (int k4 = 0; k4 < 16; ++k4) {
                const float4 xv = *(const float4*)&xlds[0][b][dh * 64 + k4 * 4];
                const float4 ww = wreg[k4];
                a = fmaf(xv.x, ww.x, a); a = fmaf(xv.y, ww.y, a);
                a = fmaf(xv.z, ww.z, a); a = fmaf(xv.w, ww.w, a);
            }
            const float full = a + __shfl_xor(a, 32);
            if (lane < 32) xps[0][ga][b * 32 + col] = full + wbias;
        }
    }
    __syncthreads();

    for (int t = 0; t < TT; ++t) {
        const int p  = t & 1;
        const int np = p ^ 1;
        const unsigned tg = (unsigned)t & TAGM;

        float acc[4][2];
        #pragma unroll
        for (int b = 0; b < 4; ++b) { acc[b][0] = 0.f; acc[b][1] = 0.f; }

        if (t == 0) {
            #pragma unroll
            for (int b = 0; b < 4; ++b) hlds[w][b][lane] = 0.f;
            // k-loop on zeros contributes 0 — skip it entirely
        } else {
            uint4v hv;
            unsigned bad;
            const char* hb = (const char*)hpub
                           + (((size_t)(p * NROW + r) * HH + k0 + lane) << 4);

            // ---- phase A: wait for low 32 lanes (producer A's columns) ----
            for (;;) {
                LOADX4(hv, hb);
                asm volatile("s_waitcnt vmcnt(0)" ::: "memory");
                __builtin_amdgcn_sched_barrier(0);
                bad = 0;
                #pragma unroll
                for (int b = 0; b < 4; ++b) bad |= (hv[b] ^ tg) & TAGM;
                const unsigned long long ball = __ballot(bad == 0);
                if ((ball & 0xffffffffull) == 0xffffffffull) break;
                __builtin_amdgcn_s_sleep(1);
            }
            #pragma unroll
            for (int b = 0; b < 4; ++b)
                hlds[w][b][lane] = __uint_as_float(hv[b] & ~TAGM);

            // ---- half-A k-loop (k4 0..7) overlaps producer B's skew ----
            #pragma unroll
            for (int k4 = 0; k4 < 8; ++k4) {
                #pragma unroll
                for (int b = 0; b < 4; ++b) {
                    const float4 h4 = *(const float4*)&hlds[w][b][k4 * 4];
                    const float2 ua = u2[k4 * 4 + 0];
                    const float2 ub = u2[k4 * 4 + 1];
                    const float2 uc = u2[k4 * 4 + 2];
                    const float2 ud = u2[k4 * 4 + 3];
                    acc[b][0] = fmaf(h4.x, ua.x, acc[b][0]);
                    acc[b][1] = fmaf(h4.x, ua.y, acc[b][1]);
                    acc[b][0] = fmaf(h4.y, ub.x, acc[b][0]);
                    acc[b][1] = fmaf(h4.y, ub.y, acc[b][1]);
                    acc[b][0] = fmaf(h4.z, uc.x, acc[b][0]);
                    acc[b][1] = fmaf(h4.z, uc.y, acc[b][1]);
                    acc[b][0] = fmaf(h4.w, ud.x, acc[b][0]);
                    acc[b][1] = fmaf(h4.w, ud.y, acc[b][1]);
                }
            }

            // ---- phase B: complete high lanes, restage, finish k-loop ----
            while (!__all(bad == 0)) {
                __builtin_amdgcn_s_sleep(1);
                LOADX4(hv, hb);
                asm volatile("s_waitcnt vmcnt(0)" ::: "memory");
                __builtin_amdgcn_sched_barrier(0);
                bad = 0;
                #pragma unroll
                for (int b = 0; b < 4; ++b) bad |= (hv[b] ^ tg) & TAGM;
            }
            #pragma unroll
            for (int b = 0; b < 4; ++b)
                hlds[w][b][lane] = __uint_as_float(hv[b] & ~TAGM);

            #pragma unroll
            for (int k4 = 8; k4 < 16; ++k4) {
                #pragma unroll
                for (int b = 0; b < 4; ++b) {
                    const float4 h4 = *(const float4*)&hlds[w][b][k4 * 4];
                    const float2 ua = u2[k4 * 4 + 0];
                    const float2 ub = u2[k4 * 4 + 1];
                    const float2 uc = u2[k4 * 4 + 2];
                    const float2 ud = u2[k4 * 4 + 3];
                    acc[b][0] = fmaf(h4.x, ua.x, acc[b][0]);
                    acc[b][1] = fmaf(h4.x, ua.y, acc[b][1]);
                    acc[b][0] = fmaf(h4.y, ub.x, acc[b][0]);
                    acc[b][1] = fmaf(h4.y, ub.y, acc[b][1]);
                    acc[b][0] = fmaf(h4.z, uc.x, acc[b][0]);
                    acc[b][1] = fmaf(h4.z, uc.y, acc[b][1]);
                    acc[b][0] = fmaf(h4.w, ud.x, acc[b][0]);
                    acc[b][1] = fmaf(h4.w, ud.y, acc[b][1]);
                }
            }
        }

        {
            const int col = lane & 31, gp = lane >> 5;
            #pragma unroll
            for (int b = 0; b < 4; ++b)
                red2[p][w][gp][b * 32 + col] = make_float2(acc[b][0], acc[b][1]);
        }
        BARRIER_LGKM();   // the single per-step barrier

        if (w < 2) {
            // ---- fused reduce + pointwise; publish h FIRST (tid < 128) ----
            __builtin_amdgcn_s_setprio(1);
            float s0 = 0.f, s1 = 0.f, s2 = 0.f, s3 = 0.f;
            #pragma unroll
            for (int ww = 0; ww < 8; ++ww) {
                const float2 a = red2[p][ww][0][tid];
                const float2 b = red2[p][ww][1][tid];
                s0 += a.x; s1 += a.y; s2 += b.x; s3 += b.y;
            }
            const float pi = xps[p][0][tid] + s0;
            const float pf = xps[p][1][tid] + s1;
            const float po = xps[p][2][tid] + s2;
            const float pg = xps[p][3][tid] + s3;

            const float ig = __fdividef(1.f, 1.f + __expf(-pi));
            const float fg = __fdividef(1.f, 1.f + __expf(-pf));
            const float og = __fdividef(1.f, 1.f + __expf(-po));
            const float tgg = __expf(-2.f * fmaxf(pg, -40.f));
            const float gg = __fdividef(1.f - tgg, 1.f + tgg);

            const float cp = creg;
            const float c  = fg * cp + ig * gg;
            creg = c;
            const float tc = __expf(-2.f * fmaxf(c, -40.f));
            const float th = __fdividef(1.f - tc, 1.f + tc);
            const float h  = og * th;

            // publish tagged h — visibility clock starts now
            const unsigned pk = (__float_as_uint(h) & ~TAGM)
                              | ((unsigned)(t + 1) & TAGM);
            unsigned* dp = hpub + (((size_t)(np * NROW + r) * HH + jjg) << 2) + b4;
            asm volatile("global_store_dword %0, %1, off sc0 sc1"
                         :: "v"(dp), "v"(pk) : "memory");
            __builtin_amdgcn_s_setprio(0);

            const float e  = og * (1.f - th * th);
            const float cd = cp * (fg * (1.f - fg)) * ufd
                           + ig * (1.f - gg * gg) * ugd
                           + gg * (ig * (1.f - ig)) * uid;
            shout[p][0][tid] = h;
            shout[p][1][tid] = fg;
            shout[p][2][tid] = e;
            shout[p][3][tid] = cd;
        } else if (w < 4) {
            // ---- drain gen t-1 outputs (waves 2-3, 2 arrays each) ----
            if (t > 0) {
                const int a2  = ((w - 2) << 1) | (lane >> 5);
                const int i32 = lane & 31;
                float* dstb = (a2 == 0) ? b_i : (a2 == 1) ? b_f
                            : (a2 == 2) ? b_o : b_g;
                const float4 v = *(const float4*)&shout[np][a2][i32 * 4];
                *(float4*)(dstb + ((size_t)(r * 4 + (i32 >> 3)) * TT + (t - 1)) * HH
                           + cg * 32 + (i32 & 7) * 4) = v;
            }
        } else {
            // ---- xproj: xp(t+1) -> xps[np] (waves 4-7); w4 stages x(t+2) ----
            if (t + 1 < TT) {
                const int col = lane & 31, dh = lane >> 5;
                #pragma unroll
                for (int b = 0; b < 4; ++b) {
                    float a = 0.f;
                    #pragma unroll
                    for (int k4 = 0; k4 < 16; ++k4) {
                        const float4 xv = *(const float4*)&xlds[np][b][dh * 64 + k4 * 4];
                        const float4 ww = wreg[k4];
                        a = fmaf(xv.x, ww.x, a); a = fmaf(xv.y, ww.y, a);
                        a = fmaf(xv.z, ww.z, a); a = fmaf(xv.w, ww.w, a);
                    }
                    const float full = a + __shfl_xor(a, 32);
                    if (lane < 32) xps[np][ga][b * 32 + col] = full + wbias;
                }
            }
            if (w == 4 && t + 2 < TT) {
                const int bx = lane >> 4, c8 = lane & 15;
                const float* xs = x + ((size_t)(r * 4 + bx) * TT + (t + 2)) * DD + c8 * 8;
                *(float4*)&xlds[p][bx][c8 * 8]     = *(const float4*)(xs);
                *(float4*)&xlds[p][bx][c8 * 8 + 4] = *(const float4*)(xs + 4);
            }
        }
    }

    // drain final step's outputs (t = TT-1, parity 1)
    __syncthreads();
    if (w == 2 || w == 3) {
        const int a2  = ((w - 2) << 1) | (lane >> 5);
        const int i32 = lane & 31;
        float* dstb = (a2 == 0) ? b_i : (a2 == 1) ? b_f : (a2 == 2) ? b_o : b_g;
        const float4 v = *(const float4*)&shout[1][a2][i32 * 4];
        *(float4*)(dstb + ((size_t)(r * 4 + (i32 >> 3)) * TT + (TT - 1)) * HH
                   + cg * 32 + (i32 & 7) * 4) = v;
    }
}

// ys[r] = dot(hs[r,:], out_w) + out_b ; one wave per row r = b*T + t
__global__ __launch_bounds__(256) void lstm_y(
    const float* __restrict__ hs, const float* __restrict__ out_w,
    const float* __restrict__ out_b, float* __restrict__ ys)
{
    const int wave = threadIdx.x >> 6;
    const int lane = threadIdx.x & 63;
    const int rr = blockIdx.x * 4 + wave;

    const float4* hv = (const float4*)(hs + (size_t)rr * HH);
    const float4* wv = (const float4*)out_w;
    float acc = 0.f;
    #pragma unroll
    for (int i = 0; i < 2; ++i) {
        float4 h4 = hv[lane * 2 + i];
        float4 w4 = wv[lane * 2 + i];
        acc += h4.x * w4.x + h4.y * w4.y + h4.z * w4.z + h4.w * w4.w;
    }
    #pragma unroll
    for (int m = 32; m >= 1; m >>= 1) acc += __shfl_xor(acc, m, 64);
    if (lane == 0) ys[rr] = acc + out_b[0];
}

extern "C" void kernel_launch(void* const* d_in, const int* in_sizes, int n_in,
                              void* d_out, int out_size, void* d_ws, size_t ws_size,
                              hipStream_t stream)
{
    const float* x    = (const float*)d_in[0];
    const float* Wi_w = (const float*)d_in[1];
    const float* Wi_b = (const float*)d_in[2];
    const float* Ui_w = (const float*)d_in[3];
    const float* Wf_w = (const float*)d_in[4];
    const float* Wf_b = (const float*)d_in[5];
    const float* Uf_w = (const float*)d_in[6];
    const float* Wo_w = (const float*)d_in[7];
    const float* Wo_b = (const float*)d_in[8];
    const float* Uo_w = (const float*)d_in[9];
    const float* Wg_w = (const float*)d_in[10];
    const float* Wg_b = (const float*)d_in[11];
    const float* Ug_w = (const float*)d_in[12];
    const float* out_w = (const float*)d_in[13];
    const float* out_b = (const float*)d_in[14];

    float* ys  = (float*)d_out;                     // [B*T]
    float* hs  = ys + (size_t)BB * TT;              // [B*T*H]
    float* fs  = hs + (size_t)BB * TT * HH;
    float* es  = fs + (size_t)BB * TT * HH;
    float* cds = es + (size_t)BB * TT * HH;

    // ws layout: [hpub 256KB][utT2 4MB]
    unsigned* hpub = (unsigned*)d_ws;
    float*    utT2 = (float*)(hpub + (size_t)2 * NROW * HH * 4);

    // zero hpub (tag 0 = unpublished; consumed tags are 1..511) every call
    hipMemsetAsync(d_ws, 0, (size_t)2 * NROW * HH * 4 * sizeof(unsigned), stream);

    uT2_kernel<<<NCG, 256, 0, stream>>>(Ui_w, Uf_w, Uo_w, Ug_w, utT2);

    lstm_persist<<<NWG, 512, 0, stream>>>(utT2, Ui_w, Uf_w, Ug_w,
                                          x, Wi_w, Wi_b, Wf_w, Wf_b,
                                          Wo_w, Wo_b, Wg_w, Wg_b,
                                          hs, fs, es, cds, hpub);

    lstm_y<<<(BB * TT) / 4, 256, 0, stream>>>(hs, out_w, out_b, ys);
}

// Round 16
// 2520.857 us; speedup vs baseline: 3.3386x; 3.3386x over previous
//
#include <hip/hip_runtime.h>
#include <math.h>

#define BB 64
#define TT 512
#define DD 128
#define HH 512
#define NROW 16
#define NCG 16
#define NWG 256
#define TAGM 511u

typedef unsigned uint4v __attribute__((ext_vector_type(4)));

// One agent-coherent 16B load: all 4 batches of one column. THE detect op.
#define LOADX4(d, ptr)                                                        \
  asm volatile("global_load_dwordx4 %0, %1, off sc0 sc1"                      \
               : "=v"(d) : "v"(ptr) : "memory")

// WG barrier ordering LDS only — global stores stay in flight across steps.
#define BARRIER_LGKM() asm volatile("s_waitcnt lgkmcnt(0)\n\ts_barrier" ::: "memory")

// ---------------------------------------------------------------------------
// Pre-kernel: utT2[cg][k][128], inner ii = 2*lane + d -> U_g[cg*32+(lane&31)][k],
// g = (lane>>5)*2 + d. Feeds register-resident per-lane U (float2 per k).
// ---------------------------------------------------------------------------
__global__ __launch_bounds__(256) void uT2_kernel(
    const float* __restrict__ Ui_w, const float* __restrict__ Uf_w,
    const float* __restrict__ Uo_w, const float* __restrict__ Ug_w,
    float* __restrict__ utT2)
{
    const int cg = blockIdx.x;
    for (int idx = threadIdx.x; idx < HH * 128; idx += 256) {
        const int k = idx >> 7, ii = idx & 127;
        const int l = ii >> 1, d = ii & 1;
        const int j = cg * 32 + (l & 31);
        const int g = ((l >> 5) << 1) + d;
        const float* U = (g == 0) ? Ui_w : (g == 1) ? Uf_w : (g == 2) ? Uo_w : Ug_w;
        utT2[((size_t)cg * HH + k) * 128 + ii] = U[(size_t)j * HH + k];
    }
}

// ---------------------------------------------------------------------------
// Persistent kernel. 256 WGs: row r = wg&15 (4 batches), cg = wg>>4 (32 cols).
// 8 waves, k-slice 64/wave, U register-resident. One lgkm barrier per step.
// h exchange: hpub[2][row][512col][4b], each dword mantissa-tagged
// (9 LSB = gen mod 512). Consumer = ONE dwordx4 per lane, tight-spin retry.
// No flags, no drains. t = 0 skips the load entirely (h0 == 0).
// Roles after barrier: w0-1 reduce+pointwise+publish (h-first, setprio);
// w2-3 drain outputs (deferred 1 step); w4-7 xproj xp(t+1), w4 stages x(t+2).
// ---------------------------------------------------------------------------
__global__ __launch_bounds__(512, 2) void lstm_persist(
    const float* __restrict__ utT2,
    const float* __restrict__ Ui_w, const float* __restrict__ Uf_w,
    const float* __restrict__ Ug_w,
    const float* __restrict__ x,
    const float* __restrict__ Wi_w, const float* __restrict__ Wi_b,
    const float* __restrict__ Wf_w, const float* __restrict__ Wf_b,
    const float* __restrict__ Wo_w, const float* __restrict__ Wo_b,
    const float* __restrict__ Wg_w, const float* __restrict__ Wg_b,
    float* __restrict__ b_i, float* __restrict__ b_f,
    float* __restrict__ b_o, float* __restrict__ b_g,
    unsigned* __restrict__ hpub)   // [2][NROW][512][4] tagged f32
{
    __shared__ float  hlds[8][4][64];         //  8 KB own-wave h slice
    __shared__ float2 red2[2][8][2][128];     // 32 KB partials (parity dbuf)
    __shared__ float  xps[2][4][128];         //  4 KB xp (parity dbuf)
    __shared__ float  shout[2][4][128];       //  4 KB outputs (parity dbuf)
    __shared__ float  xlds[2][4][128];        //  4 KB x rows (parity dbuf)

    const int tid  = threadIdx.x;
    const int w    = tid >> 6;
    const int lane = tid & 63;
    const int wg   = blockIdx.x;
    const int r    = wg & 15;
    const int cg   = wg >> 4;
    const int k0   = w << 6;

    // register-resident U slice: lane owns (col=lane&31, gates gp*2, gp*2+1)
    float2 u2[64];
    {
        const float* ub = utT2 + ((size_t)cg * HH + k0) * 128 + 2 * lane;
        #pragma unroll
        for (int k = 0; k < 64; ++k) u2[k] = *(const float2*)(ub + (size_t)k * 128);
    }

    // pointwise state (threads 0..127): b4 = tid>>5, col = tid&31
    float creg = 0.f, uid = 0.f, ufd = 0.f, ugd = 0.f;
    int jjg = 0, b4 = 0;
    if (tid < 128) {
        jjg = cg * 32 + (tid & 31);
        b4  = tid >> 5;
        uid = Ui_w[(size_t)jjg * HH + jjg];
        ufd = Uf_w[(size_t)jjg * HH + jjg];
        ugd = Ug_w[(size_t)jjg * HH + jjg];
    }

    // xproj registers (waves 4-7): gate ga = w-4, col = lane&31, dh = lane>>5
    float4 wreg[16];
    float  wbias = 0.f;
    const int ga = (w >= 4) ? (w - 4) : 0;
    if (w >= 4) {
        const int col = lane & 31, dh = lane >> 5;
        const float* Ws = (ga == 0) ? Wi_w : (ga == 1) ? Wf_w : (ga == 2) ? Wo_w : Wg_w;
        const float* Bs = (ga == 0) ? Wi_b : (ga == 1) ? Wf_b : (ga == 2) ? Wo_b : Wg_b;
        const float* base = Ws + (size_t)(cg * 32 + col) * DD + dh * 64;
        #pragma unroll
        for (int k4 = 0; k4 < 16; ++k4) wreg[k4] = *(const float4*)(base + k4 * 4);
        wbias = Bs[cg * 32 + col];
    }

    // ---- prime: stage x(0),x(1); compute xp(0) -> xps[0] ----
    if (w == 4) {
        const int bx = lane >> 4, c8 = lane & 15;
        #pragma unroll
        for (int u = 0; u < 2; ++u) {
            const float* xs = x + ((size_t)(r * 4 + bx) * TT + u) * DD + c8 * 8;
            *(float4*)&xlds[u][bx][c8 * 8]     = *(const float4*)(xs);
            *(float4*)&xlds[u][bx][c8 * 8 + 4] = *(const float4*)(xs + 4);
        }
    }
    __syncthreads();
    if (w >= 4) {
        const int col = lane & 31, dh = lane >> 5;
        #pragma unroll
        for (int b = 0; b < 4; ++b) {
            float a = 0.f;
            #pragma unroll
            for (int k4 = 0; k4 < 16; ++k4) {
                const float4 xv = *(const float4*)&xlds[0][b][dh * 64 + k4 * 4];
                const float4 ww = wreg[k4];
                a = fmaf(xv.x, ww.x, a); a = fmaf(xv.y, ww.y, a);
                a = fmaf(xv.z, ww.z, a); a = fmaf(xv.w, ww.w, a);
            }
            const float full = a + __shfl_xor(a, 32);
            if (lane < 32) xps[0][ga][b * 32 + col] = full + wbias;
        }
    }
    __syncthreads();

    for (int t = 0; t < TT; ++t) {
        const int p  = t & 1;
        const int np = p ^ 1;
        const unsigned tg = (unsigned)t & TAGM;

        // ---- acquire h(t): ONE dwordx4 per lane, tag-gated tight spin ----
        if (t == 0) {
            #pragma unroll
            for (int b = 0; b < 4; ++b) hlds[w][b][lane] = 0.f;
        } else {
            uint4v hv;
            const char* hb = (const char*)hpub
                           + (((size_t)(p * NROW + r) * HH + k0 + lane) << 4);
            for (;;) {
                LOADX4(hv, hb);
                asm volatile("s_waitcnt vmcnt(0)" ::: "memory");
                __builtin_amdgcn_sched_barrier(0);
                unsigned bad = 0;
                #pragma unroll
                for (int b = 0; b < 4; ++b) bad |= (hv[b] ^ tg) & TAGM;
                if (__all(bad == 0)) break;
            }
            #pragma unroll
            for (int b = 0; b < 4; ++b)
                hlds[w][b][lane] = __uint_as_float(hv[b] & ~TAGM);
        }

        // ---- k-loop: 4 batches x 2 outputs per lane, U in registers ----
        float acc[4][2];
        #pragma unroll
        for (int b = 0; b < 4; ++b) { acc[b][0] = 0.f; acc[b][1] = 0.f; }
        #pragma unroll
        for (int k4 = 0; k4 < 16; ++k4) {
            #pragma unroll
            for (int b = 0; b < 4; ++b) {
                const float4 h4 = *(const float4*)&hlds[w][b][k4 * 4];
                const float2 ua = u2[k4 * 4 + 0];
                const float2 ub = u2[k4 * 4 + 1];
                const float2 uc = u2[k4 * 4 + 2];
                const float2 ud = u2[k4 * 4 + 3];
                acc[b][0] = fmaf(h4.x, ua.x, acc[b][0]);
                acc[b][1] = fmaf(h4.x, ua.y, acc[b][1]);
                acc[b][0] = fmaf(h4.y, ub.x, acc[b][0]);
                acc[b][1] = fmaf(h4.y, ub.y, acc[b][1]);
                acc[b][0] = fmaf(h4.z, uc.x, acc[b][0]);
                acc[b][1] = fmaf(h4.z, uc.y, acc[b][1]);
                acc[b][0] = fmaf(h4.w, ud.x, acc[b][0]);
                acc[b][1] = fmaf(h4.w, ud.y, acc[b][1]);
            }
        }
        {
            const int col = lane & 31, gp = lane >> 5;
            #pragma unroll
            for (int b = 0; b < 4; ++b)
                red2[p][w][gp][b * 32 + col] = make_float2(acc[b][0], acc[b][1]);
        }
        BARRIER_LGKM();   // the single per-step barrier

        if (w < 2) {
            // ---- fused reduce + pointwise; publish h FIRST (tid < 128) ----
            __builtin_amdgcn_s_setprio(1);
            float s0 = 0.f, s1 = 0.f, s2 = 0.f, s3 = 0.f;
            #pragma unroll
            for (int ww = 0; ww < 8; ++ww) {
                const float2 a = red2[p][ww][0][tid];
                const float2 b = red2[p][ww][1][tid];
                s0 += a.x; s1 += a.y; s2 += b.x; s3 += b.y;
            }
            const float pi = xps[p][0][tid] + s0;
            const float pf = xps[p][1][tid] + s1;
            const float po = xps[p][2][tid] + s2;
            const float pg = xps[p][3][tid] + s3;

            const float ig = __fdividef(1.f, 1.f + __expf(-pi));
            const float fg = __fdividef(1.f, 1.f + __expf(-pf));
            const float og = __fdividef(1.f, 1.f + __expf(-po));
            const float tgg = __expf(-2.f * fmaxf(pg, -40.f));
            const float gg = __fdividef(1.f - tgg, 1.f + tgg);

            const float cp = creg;
            const float c  = fg * cp + ig * gg;
            creg = c;
            const float tc = __expf(-2.f * fmaxf(c, -40.f));
            const float th = __fdividef(1.f - tc, 1.f + tc);
            const float h  = og * th;

            // publish tagged h — visibility clock starts now
            const unsigned pk = (__float_as_uint(h) & ~TAGM)
                              | ((unsigned)(t + 1) & TAGM);
            unsigned* dp = hpub + (((size_t)(np * NROW + r) * HH + jjg) << 2) + b4;
            asm volatile("global_store_dword %0, %1, off sc0 sc1"
                         :: "v"(dp), "v"(pk) : "memory");
            __builtin_amdgcn_s_setprio(0);

            const float e  = og * (1.f - th * th);
            const float cd = cp * (fg * (1.f - fg)) * ufd
                           + ig * (1.f - gg * gg) * ugd
                           + gg * (ig * (1.f - ig)) * uid;
            shout[p][0][tid] = h;
            shout[p][1][tid] = fg;
            shout[p][2][tid] = e;
            shout[p][3][tid] = cd;
        } else if (w < 4) {
            // ---- drain gen t-1 outputs (waves 2-3, 2 arrays each) ----
            if (t > 0) {
                const int a2  = ((w - 2) << 1) | (lane >> 5);
                const int i32 = lane & 31;
                float* dstb = (a2 == 0) ? b_i : (a2 == 1) ? b_f
                            : (a2 == 2) ? b_o : b_g;
                const float4 v = *(const float4*)&shout[np][a2][i32 * 4];
                *(float4*)(dstb + ((size_t)(r * 4 + (i32 >> 3)) * TT + (t - 1)) * HH
                           + cg * 32 + (i32 & 7) * 4) = v;
            }
        } else {
            // ---- xproj: xp(t+1) -> xps[np] (waves 4-7); w4 stages x(t+2) ----
            if (t + 1 < TT) {
                const int col = lane & 31, dh = lane >> 5;
                #pragma unroll
                for (int b = 0; b < 4; ++b) {
                    float a = 0.f;
                    #pragma unroll
                    for (int k4 = 0; k4 < 16; ++k4) {
                        const float4 xv = *(const float4*)&xlds[np][b][dh * 64 + k4 * 4];
                        const float4 ww = wreg[k4];
                        a = fmaf(xv.x, ww.x, a); a = fmaf(xv.y, ww.y, a);
                        a = fmaf(xv.z, ww.z, a); a = fmaf(xv.w, ww.w, a);
                    }
                    const float full = a + __shfl_xor(a, 32);
                    if (lane < 32) xps[np][ga][b * 32 + col] = full + wbias;
                }
            }
            if (w == 4 && t + 2 < TT) {
                const int bx = lane >> 4, c8 = lane & 15;
                const float* xs = x + ((size_t)(r * 4 + bx) * TT + (t + 2)) * DD + c8 * 8;
                *(float4*)&xlds[p][bx][c8 * 8]     = *(const float4*)(xs);
                *(float4*)&xlds[p][bx][c8 * 8 + 4] = *(const float4*)(xs + 4);
            }
        }
    }

    // drain final step's outputs (t = TT-1, parity 1)
    __syncthreads();
    if (w == 2 || w == 3) {
        const int a2  = ((w - 2) << 1) | (lane >> 5);
        const int i32 = lane & 31;
        float* dstb = (a2 == 0) ? b_i : (a2 == 1) ? b_f : (a2 == 2) ? b_o : b_g;
        const float4 v = *(const float4*)&shout[1][a2][i32 * 4];
        *(float4*)(dstb + ((size_t)(r * 4 + (i32 >> 3)) * TT + (TT - 1)) * HH
                   + cg * 32 + (i32 & 7) * 4) = v;
    }
}

// ys[r] = dot(hs[r,:], out_w) + out_b ; one wave per row r = b*T + t
__global__ __launch_bounds__(256) void lstm_y(
    const float* __restrict__ hs, const float* __restrict__ out_w,
    const float* __restrict__ out_b, float* __restrict__ ys)
{
    const int wave = threadIdx.x >> 6;
    const int lane = threadIdx.x & 63;
    const int rr = blockIdx.x * 4 + wave;

    const float4* hv = (const float4*)(hs + (size_t)rr * HH);
    const float4* wv = (const float4*)out_w;
    float acc = 0.f;
    #pragma unroll
    for (int i = 0; i < 2; ++i) {
        float4 h4 = hv[lane * 2 + i];
        float4 w4 = wv[lane * 2 + i];
        acc += h4.x * w4.x + h4.y * w4.y + h4.z * w4.z + h4.w * w4.w;
    }
    #pragma unroll
    for (int m = 32; m >= 1; m >>= 1) acc += __shfl_xor(acc, m, 64);
    if (lane == 0) ys[rr] = acc + out_b[0];
}

extern "C" void kernel_launch(void* const* d_in, const int* in_sizes, int n_in,
                              void* d_out, int out_size, void* d_ws, size_t ws_size,
                              hipStream_t stream)
{
    const float* x    = (const float*)d_in[0];
    const float* Wi_w = (const float*)d_in[1];
    const float* Wi_b = (const float*)d_in[2];
    const float* Ui_w = (const float*)d_in[3];
    const float* Wf_w = (const float*)d_in[4];
    const float* Wf_b = (const float*)d_in[5];
    const float* Uf_w = (const float*)d_in[6];
    const float* Wo_w = (const float*)d_in[7];
    const float* Wo_b = (const float*)d_in[8];
    const float* Uo_w = (const float*)d_in[9];
    const float* Wg_w = (const float*)d_in[10];
    const float* Wg_b = (const float*)d_in[11];
    const float* Ug_w = (const float*)d_in[12];
    const float* out_w = (const float*)d_in[13];
    const float* out_b = (const float*)d_in[14];

    float* ys  = (float*)d_out;                     // [B*T]
    float* hs  = ys + (size_t)BB * TT;              // [B*T*H]
    float* fs  = hs + (size_t)BB * TT * HH;
    float* es  = fs + (size_t)BB * TT * HH;
    float* cds = es + (size_t)BB * TT * HH;

    // ws layout: [hpub 256KB][utT2 4MB]
    unsigned* hpub = (unsigned*)d_ws;
    float*    utT2 = (float*)(hpub + (size_t)2 * NROW * HH * 4);

    // zero hpub (tag 0 = unpublished; consumed tags are 1..511) every call
    hipMemsetAsync(d_ws, 0, (size_t)2 * NROW * HH * 4 * sizeof(unsigned), stream);

    uT2_kernel<<<NCG, 256, 0, stream>>>(Ui_w, Uf_w, Uo_w, Ug_w, utT2);

    lstm_persist<<<NWG, 512, 0, stream>>>(utT2, Ui_w, Uf_w, Ug_w,
                                          x, Wi_w, Wi_b, Wf_w, Wf_b,
                                          Wo_w, Wo_b, Wg_w, Wg_b,
                                          hs, fs, es, cds, hpub);

    lstm_y<<<(BB * TT) / 4, 256, 0, stream>>>(hs, out_w, out_b, ys);
}